// Round 4
// baseline (215.653 us; speedup 1.0000x reference)
//
#include <hip/hip_runtime.h>
#include <math.h>

#define BATCH    65536
#define FEAT     512
#define NCLASS   16
#define LAMDA    1.0f
#define LAMDA1   10.0f
#define SCALE    1.0f
#define EPS      1e-9f

constexpr int BLOCK  = 256;
constexpr int GRID   = 4096;
constexpr int NV     = BATCH * (FEAT / 4);     // 8,388,608 float4 elements
constexpr int STRIDE = GRID * BLOCK;           // 1,048,576
constexpr int ITERS  = NV / STRIDE;            // exactly 8

// Workspace layout (float slots):
//   [0, GRID)  : per-block partial sums
//   [GRID]     : item1 (gram cosine sum), computed by block GRID of k1
constexpr int WS_ITEM1 = GRID;

typedef float f4v __attribute__((ext_vector_type(4)));

// ---------------------------------------------------------------------------
// R3 lessons (from counters):
//  * VGPR_Count stayed 36 -> compiler re-sank the "up-front" loads; the
//    8-deep MLP batch never existed. Fix: pin with sched_barrier(0).
//  * FETCH_SIZE stable at 67.7 MB (= half of x) across all rounds -> the
//    512 MB poison fills do NOT evict MALL (streaming writes); the resident
//    half of x survived since upload. nt loads were PREVENTING the other
//    half from being re-inserted. Fix: plain caching loads -> x (134 MB)
//    becomes fully MALL-resident (<256 MB), stream goes MALL-BW-bound.
// Both changes touch no arithmetic -> bit-identical result.
// ---------------------------------------------------------------------------
__global__ __launch_bounds__(BLOCK) void island_main(
    const f4v* __restrict__ x,         // [BATCH * FEAT/4]
    const int* __restrict__ y,         // [BATCH]
    const f4v* __restrict__ centers4,  // [NCLASS * FEAT/4]
    float*     __restrict__ ws)        // see layout above
{
    __shared__ float wsum[4];
    __shared__ float gram[NCLASS][NCLASS];

    const int bid  = blockIdx.x;
    const int lane = threadIdx.x & 63;
    const int wid  = threadIdx.x >> 6;

    if (bid < GRID) {
        // ---------------- center-loss streaming path ----------------------
        const int tid = bid * BLOCK + threadIdx.x;

        // wave-uniform sample-row base -> y loads become s_loads.
        const int base_b = __builtin_amdgcn_readfirstlane(tid >> 7);
        const int d4     = tid & 127;

        int cls[ITERS];
        #pragma unroll
        for (int it = 0; it < ITERS; ++it)
            cls[it] = y[base_b + it * (STRIDE >> 7)];

        // Issue ALL 16 loads (8 x-stream + 8 center-gather) before any
        // consumption, then FENCE the scheduler so they cannot be re-sunk
        // into the consume loop (R3: compiler undid the batch, VGPR=36).
        // 16 x 1 KB per wave in flight covers MALL/HBM latency via MLP.
        f4v xv[ITERS];
        #pragma unroll
        for (int it = 0; it < ITERS; ++it)
            xv[it] = x[tid + it * STRIDE];         // plain: allocate in MALL

        f4v cva[ITERS];
        #pragma unroll
        for (int it = 0; it < ITERS; ++it)
            cva[it] = centers4[cls[it] * (FEAT / 4) + d4];

        __builtin_amdgcn_sched_barrier(0);          // pin the load batch

        float sum = 0.0f;
        #pragma unroll
        for (int it = 0; it < ITERS; ++it) {
            f4v e = xv[it] - cva[it];
            sum += e.x * e.x + e.y * e.y + e.z * e.z + e.w * e.w;
        }

        #pragma unroll
        for (int off = 32; off > 0; off >>= 1)
            sum += __shfl_down(sum, off, 64);

        if (lane == 0) wsum[wid] = sum;
        __syncthreads();
        if (threadIdx.x == 0)
            ws[bid] = wsum[0] + wsum[1] + wsum[2] + wsum[3];
    } else {
        // ---------------- gram + item1 (hidden under the stream) ----------
        const int j = threadIdx.x >> 4;
        const int k = threadIdx.x & 15;
        const f4v* cj = centers4 + j * (FEAT / 4);
        const f4v* ck = centers4 + k * (FEAT / 4);
        float dot = 0.0f;
        #pragma unroll 8
        for (int i = 0; i < FEAT / 4; ++i) {
            f4v a = cj[i];
            f4v b = ck[i];
            dot += a.x * b.x + a.y * b.y + a.z * b.z + a.w * b.w;
        }
        gram[j][k] = dot;
        __syncthreads();

        if (threadIdx.x == 0) {
            // EXACT old-finalize item1 arithmetic/order.
            float item1 = 0.0f;
            for (int jj = 0; jj < NCLASS; ++jj) {
                float nj = sqrtf(gram[jj][jj]);
                for (int kk = jj + 1; kk < NCLASS; ++kk) {
                    float nk = sqrtf(gram[kk][kk]);
                    item1 += gram[jj][kk] / (nj * nk + EPS) + 1.0f;
                }
            }
            ws[WS_ITEM1] = item1;
        }
    }
}

// ---------------------------------------------------------------------------
// Kernel 2 (single block): bare 4096-partial reduce + combine. ~2-3 us.
// Same reduction order as all previous rounds -> bit-identical result.
// ---------------------------------------------------------------------------
__global__ __launch_bounds__(256) void finalize_kernel(
    const float* __restrict__ ws,   // partials [GRID] + item1 at [WS_ITEM1]
    float*       __restrict__ out)  // [1]
{
    float psum = 0.0f;
    #pragma unroll
    for (int k = 0; k < GRID / 256; ++k)
        psum += ws[threadIdx.x + k * 256];
    #pragma unroll
    for (int off = 32; off > 0; off >>= 1)
        psum += __shfl_down(psum, off, 64);

    __shared__ float wsum[4];
    const int lane = threadIdx.x & 63;
    const int wid  = threadIdx.x >> 6;
    if (lane == 0) wsum[wid] = psum;
    __syncthreads();

    if (threadIdx.x == 0) {
        float total = wsum[0] + wsum[1] + wsum[2] + wsum[3];
        float loss_center = 0.5f * total * (SCALE / (float)BATCH);
        out[0] = LAMDA * (loss_center + LAMDA1 * ws[WS_ITEM1]);
    }
}

extern "C" void kernel_launch(void* const* d_in, const int* in_sizes, int n_in,
                              void* d_out, int out_size, void* d_ws, size_t ws_size,
                              hipStream_t stream) {
    const float* x       = (const float*)d_in[0];   // [BATCH, FEAT]
    const int*   y       = (const int*)d_in[1];     // [BATCH]
    const float* centers = (const float*)d_in[2];   // [NCLASS, FEAT]
    float* out = (float*)d_out;
    float* ws  = (float*)d_ws;

    island_main<<<GRID + 1, BLOCK, 0, stream>>>(
        (const f4v*)x, y, (const f4v*)centers, ws);

    finalize_kernel<<<1, 256, 0, stream>>>(ws, out);
}

// Round 5
// 206.070 us; speedup vs baseline: 1.0465x; 1.0465x over previous
//
#include <hip/hip_runtime.h>
#include <math.h>

#define BATCH    65536
#define FEAT     512
#define NCLASS   16
#define LAMDA    1.0f
#define LAMDA1   10.0f
#define SCALE    1.0f
#define EPS      1e-9f

constexpr int BLOCK  = 256;
constexpr int GRID   = 4096;
constexpr int NV     = BATCH * (FEAT / 4);     // 8,388,608 float4 elements
constexpr int STRIDE = GRID * BLOCK;           // 1,048,576
constexpr int ITERS  = NV / STRIDE;            // exactly 8

// Workspace layout (float slots):
//   [0, GRID)  : per-block partial sums
//   [GRID]     : item1 (gram cosine sum), computed by block GRID of k1
constexpr int WS_ITEM1 = GRID;

typedef float f4v __attribute__((ext_vector_type(4)));

// ---------------------------------------------------------------------------
// R4 lessons (counters):
//  * VGPR stayed 40 -> sched_barrier didn't stop load sinking; MLP batch
//    never existed at HIP level. This round forces it at ISA level:
//    16 inline-asm global_load_dwordx4 issued up-front, consumed under
//    hand-counted s_waitcnt vmcnt(7-it) (T4 counted-vmcnt discipline).
//    The waits carry "+v" ties on the loaded registers so VALU consumption
//    cannot be hoisted above them.
//  * FETCH_SIZE identical (67.7 MB) with plain vs nt loads -> MALL does not
//    re-insert this stream either way; plain loads only thrash L1/L2 and
//    evict the centers table (80 -> 107 us). Keep nt on the x stream.
// Arithmetic order untouched -> bit-identical result.
// ---------------------------------------------------------------------------
__global__ __launch_bounds__(BLOCK) void island_main(
    const f4v* __restrict__ x,         // [BATCH * FEAT/4]
    const int* __restrict__ y,         // [BATCH]
    const f4v* __restrict__ centers4,  // [NCLASS * FEAT/4]
    float*     __restrict__ ws)        // see layout above
{
    __shared__ float wsum[4];
    __shared__ float gram[NCLASS][NCLASS];

    const int bid  = blockIdx.x;
    const int lane = threadIdx.x & 63;
    const int wid  = threadIdx.x >> 6;

    if (bid < GRID) {
        // ---------------- center-loss streaming path ----------------------
        const int tid = bid * BLOCK + threadIdx.x;

        // wave-uniform sample-row base -> y loads become s_loads.
        const int base_b = __builtin_amdgcn_readfirstlane(tid >> 7);
        const int d4     = tid & 127;

        int cls[ITERS];
        #pragma unroll
        for (int it = 0; it < ITERS; ++it)
            cls[it] = y[base_b + it * (STRIDE >> 7)];

        f4v xv[ITERS];
        f4v cva[ITERS];

        // Issue the 8 nt x-loads first (slow: MALL/HBM, ~600-900 cy)...
        #pragma unroll
        for (int it = 0; it < ITERS; ++it) {
            const f4v* p = &x[tid + it * STRIDE];
            asm volatile("global_load_dwordx4 %0, %1, off nt"
                         : "=v"(xv[it]) : "v"(p));
        }
        // ...then the 8 center gathers (L1-hot, 32 KB table).
        #pragma unroll
        for (int it = 0; it < ITERS; ++it) {
            const f4v* p = &centers4[cls[it] * (FEAT / 4) + d4];
            asm volatile("global_load_dwordx4 %0, %1, off"
                         : "=v"(cva[it]) : "v"(p));
        }

        // Consume in issue order. Step it waits vmcnt(7-it): in-order counter
        // semantics mean x0..x_it AND c0..c_it have all returned. The "+v"
        // ties make the FMA data-depend on the wait -> cannot hoist.
        float sum = 0.0f;
#define STEP(IT, N)                                                          \
        asm volatile("s_waitcnt vmcnt(" #N ")"                               \
                     : "+v"(xv[IT]), "+v"(cva[IT]));                         \
        {                                                                    \
            f4v e = xv[IT] - cva[IT];                                        \
            sum += e.x * e.x + e.y * e.y + e.z * e.z + e.w * e.w;            \
        }
        STEP(0, 7) STEP(1, 6) STEP(2, 5) STEP(3, 4)
        STEP(4, 3) STEP(5, 2) STEP(6, 1) STEP(7, 0)
#undef STEP

        #pragma unroll
        for (int off = 32; off > 0; off >>= 1)
            sum += __shfl_down(sum, off, 64);

        if (lane == 0) wsum[wid] = sum;
        __syncthreads();
        if (threadIdx.x == 0)
            ws[bid] = wsum[0] + wsum[1] + wsum[2] + wsum[3];
    } else {
        // ---------------- gram + item1 (hidden under the stream) ----------
        const int j = threadIdx.x >> 4;
        const int k = threadIdx.x & 15;
        const f4v* cj = centers4 + j * (FEAT / 4);
        const f4v* ck = centers4 + k * (FEAT / 4);
        float dot = 0.0f;
        #pragma unroll 8
        for (int i = 0; i < FEAT / 4; ++i) {
            f4v a = cj[i];
            f4v b = ck[i];
            dot += a.x * b.x + a.y * b.y + a.z * b.z + a.w * b.w;
        }
        gram[j][k] = dot;
        __syncthreads();

        if (threadIdx.x == 0) {
            // EXACT old-finalize item1 arithmetic/order.
            float item1 = 0.0f;
            for (int jj = 0; jj < NCLASS; ++jj) {
                float nj = sqrtf(gram[jj][jj]);
                for (int kk = jj + 1; kk < NCLASS; ++kk) {
                    float nk = sqrtf(gram[kk][kk]);
                    item1 += gram[jj][kk] / (nj * nk + EPS) + 1.0f;
                }
            }
            ws[WS_ITEM1] = item1;
        }
    }
}

// ---------------------------------------------------------------------------
// Kernel 2 (single block): bare 4096-partial reduce + combine. ~2-3 us.
// Same reduction order as all previous rounds -> bit-identical result.
// ---------------------------------------------------------------------------
__global__ __launch_bounds__(256) void finalize_kernel(
    const float* __restrict__ ws,   // partials [GRID] + item1 at [WS_ITEM1]
    float*       __restrict__ out)  // [1]
{
    float psum = 0.0f;
    #pragma unroll
    for (int k = 0; k < GRID / 256; ++k)
        psum += ws[threadIdx.x + k * 256];
    #pragma unroll
    for (int off = 32; off > 0; off >>= 1)
        psum += __shfl_down(psum, off, 64);

    __shared__ float wsum[4];
    const int lane = threadIdx.x & 63;
    const int wid  = threadIdx.x >> 6;
    if (lane == 0) wsum[wid] = psum;
    __syncthreads();

    if (threadIdx.x == 0) {
        float total = wsum[0] + wsum[1] + wsum[2] + wsum[3];
        float loss_center = 0.5f * total * (SCALE / (float)BATCH);
        out[0] = LAMDA * (loss_center + LAMDA1 * ws[WS_ITEM1]);
    }
}

extern "C" void kernel_launch(void* const* d_in, const int* in_sizes, int n_in,
                              void* d_out, int out_size, void* d_ws, size_t ws_size,
                              hipStream_t stream) {
    const float* x       = (const float*)d_in[0];   // [BATCH, FEAT]
    const int*   y       = (const int*)d_in[1];     // [BATCH]
    const float* centers = (const float*)d_in[2];   // [NCLASS, FEAT]
    float* out = (float*)d_out;
    float* ws  = (float*)d_ws;

    island_main<<<GRID + 1, BLOCK, 0, stream>>>(
        (const f4v*)x, y, (const f4v*)centers, ws);

    finalize_kernel<<<1, 256, 0, stream>>>(ws, out);
}